// Round 10
// baseline (12.317 us; speedup 1.0000x reference)
//
#include <hip/hip_runtime.h>

// out[b,c,m] = max_n x[b,c,n] * Bt[m,n],  Bt binary {0,1}, ~3 ones per row of 2048.
// Exact sparse evaluation, TWO rows per wave with front-loaded loads:
//   - wave issues ALL 16 float4 loads (row A + row B, 8 KB each) before any
//     processing -> row B's memory time fully covers row A's ballot/gather
//     processing (intra-wave software pipeline, no extra waves needed)
//   - per 256-element chunk: one combined ballot skips empty chunks (~69%);
//     else 4 per-component ballots; gather columns derive from the
//     wave-uniform masks (no data shuffles); lanes 0..31 fmax-gather x
//   - wave-uniform nonzero count per row: cnt < 2048 -> a zero term exists
//     in the dense max -> clamp at 0; cnt == 2048 (all-ones row) -> no clamp
//   - 16 rows staged in LDS, one barrier, transposed store: each channel
//     writes 16 consecutive floats = full 64 B lines (exact 512 KB traffic)
// Every output element has exactly one writer -> plain stores, 1 dispatch.

#define HG_N_IN   2048
#define HG_N_OUT  4096
#define HG_BC     32      // BATCH * FEAT = 2*16
#define HG_RPB    16      // rows per block (8 waves x 2 rows)

typedef float nf4 __attribute__((ext_vector_type(4)));

__device__ __forceinline__ void hg_process(const nf4* __restrict__ v,
                                           const float* __restrict__ xr,
                                           int lane, float& mx, int& cnt) {
    mx = -INFINITY;
    cnt = 0;
    #pragma unroll
    for (int i = 0; i < 8; ++i) {
        const int f0 = (v[i].x != 0.0f), f1 = (v[i].y != 0.0f);
        const int f2 = (v[i].z != 0.0f), f3 = (v[i].w != 0.0f);
        unsigned long long any = __ballot((f0 | f1 | f2 | f3) != 0);
        if (any == 0ull) continue;               // wave-uniform skip (~69%)
        unsigned long long bm[4];
        bm[0] = __ballot(f0); bm[1] = __ballot(f1);
        bm[2] = __ballot(f2); bm[3] = __ballot(f3);
        #pragma unroll
        for (int j = 0; j < 4; ++j) {
            unsigned long long b = bm[j];
            while (b) {
                int s = __ffsll(b) - 1;
                b &= b - 1;
                ++cnt;                           // wave-uniform total
                int n = (((i << 6) + s) << 2) + j;
                if (lane < HG_BC) mx = fmaxf(mx, xr[n]);
            }
        }
    }
}

__global__ __launch_bounds__(512) void hg_rowmax(const nf4* __restrict__ Bt4,
                                                 const float* __restrict__ x,
                                                 float* __restrict__ out) {
    __shared__ float r[HG_RPB][HG_BC + 1];
    const int w    = threadIdx.x >> 6;           // wave 0..7
    const int lane = threadIdx.x & 63;
    const int m0   = blockIdx.x * HG_RPB;
    const int mA   = m0 + w;
    const int mB   = m0 + 8 + w;

    const nf4* rowA = Bt4 + (size_t)mA * (HG_N_IN / 4);
    const nf4* rowB = Bt4 + (size_t)mB * (HG_N_IN / 4);
    nf4 vA[8], vB[8];
    #pragma unroll
    for (int i = 0; i < 8; ++i) vA[i] = rowA[lane + (i << 6)];
    #pragma unroll
    for (int i = 0; i < 8; ++i) vB[i] = rowB[lane + (i << 6)];  // in flight over A's processing

    const float* xr = x + (size_t)(lane & (HG_BC - 1)) * HG_N_IN;

    float mxA, mxB; int cntA, cntB;
    hg_process(vA, xr, lane, mxA, cntA);
    if (lane < HG_BC)
        r[w][lane] = (cntA == HG_N_IN) ? mxA : fmaxf(mxA, 0.0f);
    hg_process(vB, xr, lane, mxB, cntB);
    if (lane < HG_BC)
        r[8 + w][lane] = (cntB == HG_N_IN) ? mxB : fmaxf(mxB, 0.0f);
    __syncthreads();

    // transposed store: 512 threads = 32 channels x 16 rows, 64 B runs per ch
    const int t  = threadIdx.x;
    const int ch = t >> 4;                       // 0..31
    const int dm = t & (HG_RPB - 1);             // 0..15
    out[(size_t)ch * HG_N_OUT + m0 + dm] = r[dm][ch];
}

extern "C" void kernel_launch(void* const* d_in, const int* in_sizes, int n_in,
                              void* d_out, int out_size, void* d_ws, size_t ws_size,
                              hipStream_t stream) {
    const float* x  = (const float*)d_in[0];     // [2,16,2048] f32
    const nf4* Bt4  = (const nf4*)d_in[1];       // [4096,2048] f32 as float4
    float* out = (float*)d_out;                  // [2,16,4096] f32

    // 8 waves x 2 rows = 16 rows per 512-thread block -> 256 blocks (1/CU)
    hg_rowmax<<<HG_N_OUT / HG_RPB, 512, 0, stream>>>(Bt4, x, out);
}

// Round 11
// 11.138 us; speedup vs baseline: 1.1058x; 1.1058x over previous
//
#include <hip/hip_runtime.h>

// out[b,c,m] = max_n x[b,c,n] * Bt[m,n],  Bt binary {0,1}, ~3 ones per row of 2048.
// Exact sparse evaluation, one wave per row, 8 rows per 512-thread block:
//   - wave loads its 8 KB row as 8 float4 per lane (coalesced, all in flight;
//     plain loads so the 256 MB L3 retains Bt across graph replays)
//   - one combined ballot per 256-element chunk skips empty chunks (~69%)
//   - non-empty chunks: 4 per-component ballots; gather addresses derive
//     purely from the wave-uniform masks (no data shuffles) -> all x gathers
//     issue back-to-back, the fmax chain waits on latency only once
//   - wave-uniform nonzero count: cnt < 2048 -> a zero term exists -> clamp
//     at 0 (the dense x*0 terms); cnt == 2048 -> no clamp (all-ones row)
//   - results staged in LDS, stored transposed (full 64 B lines, exact 512 KB)
// Every output element has exactly one writer -> plain stores, 1 dispatch.
//
// Tuning history (refuted alternatives, all single-variable unless noted):
//   R3  block-per-row + LDS compaction          12.9 us
//   R4  wave-per-row, per-hit __shfl            13.0 us
//   R5  + staged transposed stores              12.3 us
//   R7  + per-component ballots + nt loads      11.6 us
//   R8  - nt loads (this kernel)                11.1 us  <- best
//   R9  2 waves/row, 32 waves/CU (TLP)          11.6 us  refuted
//   R10 2 rows/wave, front-loaded (ILP)         12.3 us  refuted

#define HG_N_IN   2048
#define HG_N_OUT  4096
#define HG_BC     32      // BATCH * FEAT = 2*16
#define HG_RPB    8       // rows per block (= waves per block)

typedef float nf4 __attribute__((ext_vector_type(4)));

__global__ __launch_bounds__(512) void hg_rowmax(const nf4* __restrict__ Bt4,
                                                 const float* __restrict__ x,
                                                 float* __restrict__ out) {
    __shared__ float r[HG_RPB][HG_BC + 1];
    const int w    = threadIdx.x >> 6;           // wave id = row within block
    const int lane = threadIdx.x & 63;
    const int m0   = blockIdx.x * HG_RPB;
    const int m    = m0 + w;

    const nf4* row = Bt4 + (size_t)m * (HG_N_IN / 4);
    nf4 v[8];
    #pragma unroll
    for (int i = 0; i < 8; ++i)
        v[i] = row[lane + (i << 6)];             // plain loads: L3 retains Bt

    const float* xr = x + (size_t)(lane & (HG_BC - 1)) * HG_N_IN;
    float mx = -INFINITY;
    int cnt = 0;

    #pragma unroll
    for (int i = 0; i < 8; ++i) {
        const int f0 = (v[i].x != 0.0f), f1 = (v[i].y != 0.0f);
        const int f2 = (v[i].z != 0.0f), f3 = (v[i].w != 0.0f);
        unsigned long long any = __ballot((f0 | f1 | f2 | f3) != 0);
        if (any == 0ull) continue;               // wave-uniform skip (~69%)
        unsigned long long bm[4];
        bm[0] = __ballot(f0); bm[1] = __ballot(f1);
        bm[2] = __ballot(f2); bm[3] = __ballot(f3);
        #pragma unroll
        for (int j = 0; j < 4; ++j) {
            unsigned long long b = bm[j];
            while (b) {
                int s = __ffsll(b) - 1;
                b &= b - 1;
                ++cnt;                           // wave-uniform total
                int n = (((i << 6) + s) << 2) + j;
                if (lane < HG_BC) mx = fmaxf(mx, xr[n]);  // no cross-lane dep
            }
        }
    }

    float res = (cnt == HG_N_IN) ? mx : fmaxf(mx, 0.0f);  // clamp iff a zero exists
    if (lane < HG_BC) r[w][lane] = res;
    __syncthreads();

    // transposed store: 256 threads cover 8 rows x 32 channels, 32 B runs per bc
    const int t = threadIdx.x;
    if (t < HG_BC * HG_RPB) {
        const int bc = t >> 3;                   // 0..31
        const int dm = t & (HG_RPB - 1);         // 0..7
        out[(size_t)bc * HG_N_OUT + m0 + dm] = r[dm][bc];
    }
}

extern "C" void kernel_launch(void* const* d_in, const int* in_sizes, int n_in,
                              void* d_out, int out_size, void* d_ws, size_t ws_size,
                              hipStream_t stream) {
    const float* x  = (const float*)d_in[0];     // [2,16,2048] f32
    const nf4* Bt4  = (const nf4*)d_in[1];       // [4096,2048] f32 as float4
    float* out = (float*)d_out;                  // [2,16,4096] f32

    // 8 waves per block, one row per wave -> 512 blocks (2 blocks/CU)
    hg_rowmax<<<HG_N_OUT / HG_RPB, 512, 0, stream>>>(Bt4, x, out);
}